// Round 1
// baseline (2066.145 us; speedup 1.0000x reference)
//
#include <hip/hip_runtime.h>
#include <hip/hip_bf16.h>

// Problem constants
// B=4, S=2048, D_MODEL=1024, H=16, E=64 (d_head)
// M = B*S = 8192 rows
// Internal layouts:
//   q,k,v : [bh=64][s=2048][e=64]   (bh = b*16+h)
//   z     : [b][s][h][e]  == row-major [8192][1024] for the O-proj GEMM
//   pattern (output) : [b][h][q][k] = [64][2048][2048]
//   attn_out (output): [8192][1024]

// ---------------------------------------------------------------------------
// Kernel 1: fused QKV projection.  C[64x64] = x[r0:r0+64, :1024] * W_h[:1024, :64]
// grid: (128, 48); blockIdx.y: which = y>>4 (0=Q,1=K,2=V), h = y&15
// ---------------------------------------------------------------------------
__global__ __launch_bounds__(256) void k_proj_qkv(
    const float* __restrict__ x,
    const float* __restrict__ Wq, const float* __restrict__ bq,
    const float* __restrict__ Wk, const float* __restrict__ bk,
    const float* __restrict__ Wv, const float* __restrict__ bv,
    float* __restrict__ oq, float* __restrict__ ok, float* __restrict__ ov)
{
    const int bm    = blockIdx.x;
    const int which = blockIdx.y >> 4;
    const int h     = blockIdx.y & 15;
    const float* W    = (which == 0) ? Wq : (which == 1) ? Wk : Wv;
    const float* bias = (which == 0) ? bq : (which == 1) ? bk : bv;
    float* out        = (which == 0) ? oq : (which == 1) ? ok : ov;
    W += (size_t)h * 1024 * 64;

    __shared__ float As[16][68];   // transposed: As[k][row]
    __shared__ float Bs[16][68];   // Bs[k][col]

    const int tid = threadIdx.x;
    const int tx  = tid & 15;
    const int ty  = tid >> 4;
    const int r0  = bm * 64;

    float acc[4][4] = {};

    for (int kb = 0; kb < 1024; kb += 16) {
        {   // A tile 64x16 -> transposed
            int row = tid >> 2;
            int c4  = (tid & 3) * 4;
            float4 a = *(const float4*)&x[(size_t)(r0 + row) * 1024 + kb + c4];
            As[c4 + 0][row] = a.x; As[c4 + 1][row] = a.y;
            As[c4 + 2][row] = a.z; As[c4 + 3][row] = a.w;
        }
        {   // B tile 16x64
            int rr = tid >> 4;
            int c4 = (tid & 15) * 4;
            *(float4*)&Bs[rr][c4] = *(const float4*)&W[(size_t)(kb + rr) * 64 + c4];
        }
        __syncthreads();
        #pragma unroll
        for (int kk = 0; kk < 16; ++kk) {
            float4 a4 = *(const float4*)&As[kk][ty * 4];
            float4 b4 = *(const float4*)&Bs[kk][tx * 4];
            float av[4] = {a4.x, a4.y, a4.z, a4.w};
            float bv4[4] = {b4.x, b4.y, b4.z, b4.w};
            #pragma unroll
            for (int i = 0; i < 4; ++i)
                #pragma unroll
                for (int j = 0; j < 4; ++j)
                    acc[i][j] += av[i] * bv4[j];
        }
        __syncthreads();
    }

    const int b  = r0 >> 11;           // row block never crosses batch boundary
    const int s0 = (r0 & 2047) + ty * 4;
    float4 bias4 = *(const float4*)&bias[h * 64 + tx * 4];
    float bb[4] = {bias4.x, bias4.y, bias4.z, bias4.w};
    #pragma unroll
    for (int i = 0; i < 4; ++i) {
        int s = s0 + i;
        float4 o;
        o.x = acc[i][0] + bb[0]; o.y = acc[i][1] + bb[1];
        o.z = acc[i][2] + bb[2]; o.w = acc[i][3] + bb[3];
        *(float4*)&out[(((size_t)(b * 16 + h) * 2048 + s) * 64) + tx * 4] = o;
    }
}

// ---------------------------------------------------------------------------
// Kernel 2: scores (q.k^T / 8) + causal mask + softmax + pattern write.
// One wave per q-row, 4 waves per block.  grid: (64, 512)
// Scores parked in LDS (dynamic tile loop, no register arrays).
// ---------------------------------------------------------------------------
__global__ __launch_bounds__(256) void k_scores_softmax(
    const float* __restrict__ qb,   // [64][2048][64]
    const float* __restrict__ kb,   // [64][2048][64]
    float* __restrict__ pattern)    // [64][2048][2048]
{
    const int bh   = blockIdx.x;
    const int q0   = blockIdx.y * 4;
    const int tid  = threadIdx.x;
    const int wid  = tid >> 6;
    const int lane = tid & 63;
    const int q    = q0 + wid;

    __shared__ float ks[64][68];
    __shared__ float sl[4][32][64];

    // q row into registers (wave-uniform addresses)
    const float* qrow = qb + ((size_t)bh * 2048 + q) * 64;
    float4 qv[16];
    #pragma unroll
    for (int i = 0; i < 16; ++i) qv[i] = *(const float4*)&qrow[i * 4];

    const int ntiles = q0 / 64 + 1;       // block-uniform causal tile count
    const float* kbase = kb + (size_t)bh * 2048 * 64;

    float runmax = -1e30f;
    for (int t = 0; t < ntiles; ++t) {
        // stage k tile [64][64] (4 float4 per thread)
        #pragma unroll
        for (int rep = 0; rep < 4; ++rep) {
            int idx = tid + rep * 256;       // 0..1023 float4 units
            int r   = idx >> 4;              // 0..63
            int c4  = (idx & 15) * 4;        // 0..60
            *(float4*)&ks[r][c4] =
                *(const float4*)&kbase[(size_t)(t * 64 + r) * 64 + c4];
        }
        __syncthreads();

        int kk = t * 64 + lane;
        float s = 0.f;
        #pragma unroll
        for (int i = 0; i < 16; ++i) {
            float4 k4 = *(const float4*)&ks[lane][i * 4];
            s += qv[i].x * k4.x + qv[i].y * k4.y + qv[i].z * k4.z + qv[i].w * k4.w;
        }
        s *= 0.125f;
        if (kk > q) s = -1e30f;
        sl[wid][t][lane] = s;
        runmax = fmaxf(runmax, s);
        __syncthreads();
    }

    // wave-wide max
    #pragma unroll
    for (int off = 32; off; off >>= 1)
        runmax = fmaxf(runmax, __shfl_xor(runmax, off));

    // exp + sum (store p back to LDS)
    float sum = 0.f;
    for (int t = 0; t < ntiles; ++t) {
        float p = __expf(sl[wid][t][lane] - runmax);
        sl[wid][t][lane] = p;
        sum += p;
    }
    #pragma unroll
    for (int off = 32; off; off >>= 1)
        sum += __shfl_xor(sum, off);
    const float inv = 1.f / sum;

    float* prow = pattern + ((size_t)bh * 2048 + q) * 2048;
    for (int t = 0; t < 32; ++t) {
        float p = 0.f;
        if (t < ntiles) {
            int kk = t * 64 + lane;
            p = (kk <= q) ? sl[wid][t][lane] * inv : 0.f;
        }
        prow[t * 64 + lane] = p;
    }
}

// ---------------------------------------------------------------------------
// Kernel 3: PV.  z[s][e] = sum_k pattern[q][k] * v[k][e], causal k-tile skip.
// grid: (32, 64): x = q-tile, y = bh.  BM=64, BN=64(=E), BK=32.
// ---------------------------------------------------------------------------
__global__ __launch_bounds__(256) void k_pv(
    const float* __restrict__ pattern,  // [64][2048][2048]
    const float* __restrict__ vb,       // [64][2048][64]
    float* __restrict__ z)              // [b][s][h][e]
{
    const int qt = blockIdx.x;
    const int bh = blockIdx.y;
    const int b  = bh >> 4, h = bh & 15;
    const int q0 = qt * 64;
    const int nk = q0 + 64;            // causal: k < q0+64

    __shared__ float Ps[32][68];       // transposed: Ps[k][q]
    __shared__ float Vs[32][68];       // Vs[k][e]

    const int tid = threadIdx.x;
    const int tx  = tid & 15;
    const int ty  = tid >> 4;

    const float* pbase = pattern + (size_t)bh * 2048 * 2048;
    const float* vbase = vb + (size_t)bh * 2048 * 64;

    float acc[4][4] = {};

    for (int kbb = 0; kbb < nk; kbb += 32) {
        #pragma unroll
        for (int rep = 0; rep < 2; ++rep) {   // P tile 64x32 -> transposed
            int idx = tid + rep * 256;        // 0..511 f4 units (64 rows x 8 f4)
            int rr  = idx >> 3;
            int cc  = (idx & 7) * 4;
            float4 p4 = *(const float4*)&pbase[(size_t)(q0 + rr) * 2048 + kbb + cc];
            Ps[cc + 0][rr] = p4.x; Ps[cc + 1][rr] = p4.y;
            Ps[cc + 2][rr] = p4.z; Ps[cc + 3][rr] = p4.w;
        }
        #pragma unroll
        for (int rep = 0; rep < 2; ++rep) {   // V tile 32x64
            int idx = tid + rep * 256;        // 0..511 f4 units (32 rows x 16 f4)
            int rr  = idx >> 4;
            int cc  = (idx & 15) * 4;
            *(float4*)&Vs[rr][cc] = *(const float4*)&vbase[(size_t)(kbb + rr) * 64 + cc];
        }
        __syncthreads();
        #pragma unroll
        for (int kk = 0; kk < 32; ++kk) {
            float4 a4 = *(const float4*)&Ps[kk][ty * 4];
            float4 b4 = *(const float4*)&Vs[kk][tx * 4];
            float av[4] = {a4.x, a4.y, a4.z, a4.w};
            float bv4[4] = {b4.x, b4.y, b4.z, b4.w};
            #pragma unroll
            for (int i = 0; i < 4; ++i)
                #pragma unroll
                for (int j = 0; j < 4; ++j)
                    acc[i][j] += av[i] * bv4[j];
        }
        __syncthreads();
    }

    #pragma unroll
    for (int i = 0; i < 4; ++i) {
        int s = q0 + ty * 4 + i;
        float4 o = {acc[i][0], acc[i][1], acc[i][2], acc[i][3]};
        *(float4*)&z[(((size_t)(b * 2048 + s) * 16 + h) * 64) + tx * 4] = o;
    }
}

// ---------------------------------------------------------------------------
// Kernel 4: O projection.  attn_out[m][n] = sum_k z[m][k] * Wo[k][n] + bo[n]
// grid: (128, 16).  BM=64, BN=64, BK=16.
// ---------------------------------------------------------------------------
__global__ __launch_bounds__(256) void k_oproj(
    const float* __restrict__ z,     // [8192][1024]
    const float* __restrict__ Wo,    // [1024][1024]  (k = h*64+e)
    const float* __restrict__ bo,    // [1024]
    float* __restrict__ out)         // [8192][1024]
{
    const int r0 = blockIdx.x * 64;
    const int c0 = blockIdx.y * 64;

    __shared__ float As[16][68];
    __shared__ float Bs[16][68];

    const int tid = threadIdx.x;
    const int tx  = tid & 15;
    const int ty  = tid >> 4;

    float acc[4][4] = {};

    for (int kb = 0; kb < 1024; kb += 16) {
        {
            int row = tid >> 2;
            int c4  = (tid & 3) * 4;
            float4 a = *(const float4*)&z[(size_t)(r0 + row) * 1024 + kb + c4];
            As[c4 + 0][row] = a.x; As[c4 + 1][row] = a.y;
            As[c4 + 2][row] = a.z; As[c4 + 3][row] = a.w;
        }
        {
            int rr = tid >> 4;
            int c4 = (tid & 15) * 4;
            *(float4*)&Bs[rr][c4] =
                *(const float4*)&Wo[(size_t)(kb + rr) * 1024 + c0 + c4];
        }
        __syncthreads();
        #pragma unroll
        for (int kk = 0; kk < 16; ++kk) {
            float4 a4 = *(const float4*)&As[kk][ty * 4];
            float4 b4 = *(const float4*)&Bs[kk][tx * 4];
            float av[4] = {a4.x, a4.y, a4.z, a4.w};
            float bv4[4] = {b4.x, b4.y, b4.z, b4.w};
            #pragma unroll
            for (int i = 0; i < 4; ++i)
                #pragma unroll
                for (int j = 0; j < 4; ++j)
                    acc[i][j] += av[i] * bv4[j];
        }
        __syncthreads();
    }

    float4 bo4 = *(const float4*)&bo[c0 + tx * 4];
    float bb[4] = {bo4.x, bo4.y, bo4.z, bo4.w};
    #pragma unroll
    for (int i = 0; i < 4; ++i) {
        int row = r0 + ty * 4 + i;
        float4 o;
        o.x = acc[i][0] + bb[0]; o.y = acc[i][1] + bb[1];
        o.z = acc[i][2] + bb[2]; o.w = acc[i][3] + bb[3];
        *(float4*)&out[(size_t)row * 1024 + c0 + tx * 4] = o;
    }
}

// ---------------------------------------------------------------------------
extern "C" void kernel_launch(void* const* d_in, const int* in_sizes, int n_in,
                              void* d_out, int out_size, void* d_ws, size_t ws_size,
                              hipStream_t stream) {
    const float* x  = (const float*)d_in[0];
    const float* Wq = (const float*)d_in[1];
    const float* bq = (const float*)d_in[2];
    const float* Wk = (const float*)d_in[3];
    const float* bk = (const float*)d_in[4];
    const float* Wv = (const float*)d_in[5];
    const float* bv = (const float*)d_in[6];
    const float* Wo = (const float*)d_in[7];
    const float* bo = (const float*)d_in[8];

    float* out      = (float*)d_out;
    float* attn_out = out;                          // 8192*1024 floats
    float* pattern  = out + (size_t)8192 * 1024;    // 64*2048*2048 floats

    const size_t PER = (size_t)64 * 2048 * 64;      // 8.39M floats each
    float* q = (float*)d_ws;
    float* k = q + PER;
    float* v = k + PER;
    float* z = v + PER;                             // [8192][1024]

    k_proj_qkv     <<<dim3(128, 48), 256, 0, stream>>>(x, Wq, bq, Wk, bk, Wv, bv, q, k, v);
    k_scores_softmax<<<dim3(64, 512), 256, 0, stream>>>(q, k, pattern);
    k_pv           <<<dim3(32, 64),  256, 0, stream>>>(pattern, v, z);
    k_oproj        <<<dim3(128, 16), 256, 0, stream>>>(z, Wo, bo, attn_out);
}